// Round 10
// baseline (52.986 us; speedup 1.0000x reference)
//
#include <hip/hip_runtime.h>
#include <hip/hip_bf16.h>

typedef short bf16x8 __attribute__((ext_vector_type(8)));
typedef float f32x4  __attribute__((ext_vector_type(4)));
typedef unsigned short u16;

#define Bc    16
#define Vc    20
#define MFc   32
#define MTc   8
#define NPc   4
#define Kc    3
#define Rc    12
#define Dc    128
#define NOUTc 64

#define TOTAL_UNITS (Bc * Vc * MTc * MFc)   // 81920 ; u = bv*256 + f*8 + t
#define XPU 144                             // rel floats per unit
#define NBLOCKS 1024                        // 4 blocks/CU
#define UPB 80                              // units per block
#define NBATCH 5                            // 16-unit batches per block
#define ZLD 136                             // zp row length (u16), 16B-aligned pad

// d_ws tables (bf16 bits):
//   diagB[128 d][32 r]  @ 0     : W_rel diagonal, r>=12 zeroed (P1 B-operand)
//   Wb   [64 n][128 d]  @ 4096  : out_w transposed (P2 B-operand)
__global__ void setup_tabs(const float* __restrict__ W_rel,
                           const float* __restrict__ out_w,
                           u16* __restrict__ ws) {
    const int i = blockIdx.x * 256 + threadIdx.x;
    if (i < 128 * 32) {
        const int d = i >> 5, r = i & 31;
        const float v = (r < Rc) ? W_rel[(r * Dc + d) * Dc + d] : 0.f;
        union { __hip_bfloat16 h; u16 u; } cv; cv.h = __float2bfloat16(v);
        ws[i] = cv.u;
    } else if (i < 128 * 32 + 64 * 128) {
        const int j = i - 128 * 32;
        const int n = j >> 7, d = j & 127;
        union { __hip_bfloat16 h; u16 u; } cv;
        cv.h = __float2bfloat16(out_w[d * NOUTc + n]);
        ws[i] = cv.u;
    }
}

__global__ __launch_bounds__(256)
void gal_kernel(const float* __restrict__ src,    // [B,V,MT,MF,D]
                const float* __restrict__ rel,    // [u][144]
                const u16*   __restrict__ diagB,  // [128][32] bf16
                const u16*   __restrict__ Wb,     // [64][128] bf16
                const float* __restrict__ attn_w, // [NOUT+D]
                const float* __restrict__ out_b,  // [NOUT]
                float* __restrict__ out)          // [B,V,NOUT]
{
    // zp[buf][unit-in-batch][d] bf16, p-summed in P1 (K=128 for P2)
    __shared__ __align__(16) u16 zp[2][16][ZLD];   // 8.7 KB

    const int tid  = threadIdx.x;
    const int lane = tid & 63;
    const int wv   = tid >> 6;
    const int c    = lane & 15;   // MFMA col / A-row index
    const int g    = lane >> 4;   // MFMA k-group / C row-group

    const int u_base = blockIdx.x * UPB;
    const int bv0    = u_base >> 8;

    // ---- hoisted loop-invariant register tables ----
    // P1 B-frags (diag), one per d-tile: 32 VGPR
    bf16x8 dgf[8];
#pragma unroll
    for (int t = 0; t < 8; ++t)
        dgf[t] = *(const bf16x8*)(diagB + (t * 16 + c) * 32 + g * 8);
    // P2 B-frags (out_w), K=128: 16 VGPR
    bf16x8 wbf[4];
#pragma unroll
    for (int ks = 0; ks < 4; ++ks)
        wbf[ks] = *(const bf16x8*)(Wb + (wv * 16 + c) * Dc + ks * 32 + g * 8);

    const float LOG2E = 1.4426950408889634f;
    float aw_r[8];
#pragma unroll
    for (int t = 0; t < 8; ++t)
        aw_r[t] = attn_w[NOUTc + t * 16 + c] * LOG2E;
    const float ob = out_b[wv * 16 + c];

    // P1 A-frag geometry: A-row = c -> (p = c>>2, k = c&3; k==3 pad dups k=2).
    const int pA  = c >> 2, klA = c & 3;
    const int rr  = pA * 3 + (klA < 3 ? klA : 2);
    const int ao0 = rr * Rc + (g & 1) * 8;
    const int ao1 = (g == 0) ? (ao0 + 4) : ao0;
    const bool vlo = (g <= 1);
    const bool vhi = (g == 0);

    const f32x4 zero4 = {0.f, 0.f, 0.f, 0.f};
    float accA = 0.f, accB = 0.f;

    for (int b = 0; b < NBATCH; ++b) {
        const int X   = b & 1;
        const int ub0 = u_base + b * 16;

        // ---- P1: each wave computes 4 units -> zp rows wv*4+j ----
        for (int j = 0; j < 4; ++j) {
            const int u = ub0 + wv * 4 + j;
            const float* __restrict__ xu = rel + u * XPU;
            const float4 La = *(const float4*)(xu + ao0);
            const float4 Lb = *(const float4*)(xu + ao1);

            const int t8 = u & 7, f5 = (u >> 3) & 31, ubv = u >> 8;
            const float* __restrict__ sp = src + ((ubv * MTc + t8) * MFc + f5) * Dc;
            float sld[8];
#pragma unroll
            for (int t = 0; t < 8; ++t) sld[t] = sp[t * 16 + c];

            // A-fragment: fp32 -> bf16 pairs, zero padded k-slots
            union { __hip_bfloat162 h; unsigned int q; } q0, q1, q2, q3;
            q0.h = __float22bfloat162_rn(make_float2(La.x, La.y));
            q1.h = __float22bfloat162_rn(make_float2(La.z, La.w));
            q2.h = __float22bfloat162_rn(make_float2(Lb.x, Lb.y));
            q3.h = __float22bfloat162_rn(make_float2(Lb.z, Lb.w));
            union { bf16x8 v; unsigned int q[4]; } af;
            af.q[0] = vlo ? q0.q : 0u;
            af.q[1] = vlo ? q1.q : 0u;
            af.q[2] = vhi ? q2.q : 0u;
            af.q[3] = vhi ? q3.q : 0u;

            // 8 MFMAs over d-tiles; k-product local (regs 0..2, own p=g)
            float w[8], lp = 0.f;
#pragma unroll
            for (int t = 0; t < 8; ++t) {
                const f32x4 pa =
                    __builtin_amdgcn_mfma_f32_16x16x32_bf16(af.v, dgf[t], zero4, 0, 0, 0);
                w[t] = pa[0] * pa[1] * pa[2];
                lp = fmaf(w[t], sld[t] * aw_r[t], lp);
            }
            lp += __shfl_xor(lp, 1);
            lp += __shfl_xor(lp, 2);
            lp += __shfl_xor(lp, 4);
            lp += __shfl_xor(lp, 8);
            const float lA = lp;                    // logit of p = g
            const float lB = __shfl_xor(lp, 16);    // p = g^1
            const float lC = __shfl_xor(lp, 32);    // p = g^2
            const float lD = __shfl_xor(lB, 32);    // p = g^3

            // softmax over 4 paths, log2 domain (uniform terms cancel)
            const float m   = fmaxf(fmaxf(lA, lB), fmaxf(lC, lD));
            const float eS  = exp2f(lA - m);
            const float sum = eS + exp2f(lB - m) + exp2f(lC - m) + exp2f(lD - m);
            const float aS  = eS * __builtin_amdgcn_rcpf(sum);  // own path weight

            // p-sum in registers: zsum[d] = sum_p a_p * w_p[d]; z = s * zsum
            float zb[8];
#pragma unroll
            for (int t = 0; t < 8; ++t) {
                float v = aS * w[t];
                v += __shfl_xor(v, 16);
                v += __shfl_xor(v, 32);
                zb[t] = v * sld[t];
            }
            // 16-lane contiguous 32B stores: conflict-free
            if (lane < 16) {
                u16* zr = &zp[X][wv * 4 + j][c];
#pragma unroll
                for (int t = 0; t < 8; ++t) {
                    union { __hip_bfloat16 h; u16 u; } cv;
                    cv.h = __float2bfloat16(zb[t]);
                    zr[t * 16] = cv.u;
                }
            }
        }

        __syncthreads();   // zp[X] complete; zp[X^1] untouched by this batch

        // ---- P2: [16 units x 128] @ Wb -> C[units, n]; wave = N-tile wv ----
        f32x4 ca = zero4;
#pragma unroll
        for (int ks = 0; ks < 4; ++ks) {
            const bf16x8 az = *(const bf16x8*)(&zp[X][c][ks * 32 + g * 8]);
            ca = __builtin_amdgcn_mfma_f32_16x16x32_bf16(az, wbf[ks], ca, 0, 0, 0);
        }

        // epilogue: bias + relu per unit-row (rows g*4+i), sum my 4 rows
        float su = 0.f;
#pragma unroll
        for (int i = 0; i < 4; ++i)
            su += fmaxf(ca[i] + ob, 0.f);
        if ((ub0 >> 8) == bv0) accA += su; else accB += su;
        // NOTE: 16-unit batches never straddle a bv boundary (256 % 16 == 0)
    }

    // reduce over row-groups (g) and emit: wave owns distinct n-range
    accA += __shfl_xor(accA, 16); accA += __shfl_xor(accA, 32);
    accB += __shfl_xor(accB, 16); accB += __shfl_xor(accB, 32);
    if (lane < 16) {
        atomicAdd(&out[bv0 * NOUTc + wv * 16 + lane], accA);
        const int bvL = (u_base + UPB - 1) >> 8;
        if (bvL != bv0) atomicAdd(&out[bvL * NOUTc + wv * 16 + lane], accB);
    }
}

extern "C" void kernel_launch(void* const* d_in, const int* in_sizes, int n_in,
                              void* d_out, int out_size, void* d_ws, size_t ws_size,
                              hipStream_t stream) {
    const float* src    = (const float*)d_in[0];  // source_embed
    const float* rel    = (const float*)d_in[1];  // rel_index
    // d_in[2] = s        (cancels in softmax)
    const float* W_rel  = (const float*)d_in[3];
    const float* attn_w = (const float*)d_in[4];
    // d_in[5] = attn_b   (cancels in softmax)
    const float* out_w  = (const float*)d_in[6];
    const float* out_b  = (const float*)d_in[7];
    float* out  = (float*)d_out;
    u16*   tabs = (u16*)d_ws;                     // 24 KB of bf16 tables

    hipMemsetAsync(out, 0, (size_t)out_size * sizeof(float), stream);
    setup_tabs<<<48, 256, 0, stream>>>(W_rel, out_w, tabs);
    gal_kernel<<<NBLOCKS, 256, 0, stream>>>(src, rel, tabs, tabs + 128 * 32,
                                            attn_w, out_b, out);
}